// Round 13
// baseline (421.351 us; speedup 1.0000x reference)
//
#include <hip/hip_runtime.h>
#include <math.h>

#define N_LAYERS 6
#define NW (N_LAYERS * 4)

// POD 4-float vector (safe in LDS, no C++ ctor)
typedef float vf4 __attribute__((ext_vector_type(4)));

// ---------------------------------------------------------------------------
// Fused kernel, full grid (2048 blocks x 256 thr x M=2 = 2^20 samples).
// Phase P (per block, redundant, ~1.5 us): build W (16x16 complex) from the
//   24 RX gates + CNOT rings, S_q = Re(W^dag Z_q W), contract to the 81-term
//   table  out_q(x) = sum_t C_q[t] prod_p {1,cos x_p,sin x_p}[t_p]  -> LDS.
// Phase E: M=2 samples/thread; each ds_read_b128 coefficient broadcast feeds
//   8 FMAs (two samples x vec4). M=2 halves total per-wave table delivery —
//   the measured wall (R12 proved delivery-per-wave is fundamental: s_load
//   path 35 us, per-lane broadcast 18 us, both bounded by per-wave fan-out).
// x is prefetched BEFORE the prep barriers so HBM latency hides under prep.
// 1D/suffix scalars only (2D locals scratch-spill: R7). LB(256,4): <=128 VGPR.
// ---------------------------------------------------------------------------
__global__ __launch_bounds__(256, 4) void qfused_kernel(
    const float* __restrict__ x, const float* __restrict__ weights,
    float* __restrict__ out, int B)
{
    __shared__ float Wr[16][16], Wi[16][16];
    __shared__ float S4[4][16][16];
    __shared__ float wc[NW], ws[NW];
    __shared__ vf4 Cs[81];

    const int tid = threadIdx.x;
    int b0 = blockIdx.x * 512 + tid;
    int b1 = b0 + 256;
    b0 = (b0 < B) ? b0 : (B - 1);   // clamp (exact when B = 2^20)
    b1 = (b1 < B) ? b1 : (B - 1);

    // ---- prefetch x before the prep barriers (latency hides under prep)
    const float4* __restrict__ xv4 = reinterpret_cast<const float4*>(x);
    const float4 x0 = xv4[b0];
    const float4 x1 = xv4[b1];

    // ---- P0: shared gate trig
    if (tid < NW) {
        float t = weights[tid] * 0.5f;
        wc[tid] = __cosf(t);
        ws[tid] = __sinf(t);
    }
    __syncthreads();

    // ---- P1: threads 0..15 build column `tid` of W (registers, unrolled)
    if (tid < 16) {
        float re[16], im[16];
#pragma unroll
        for (int k = 0; k < 16; ++k) { re[k] = (k == tid) ? 1.f : 0.f; im[k] = 0.f; }
#pragma unroll 1
        for (int l = 0; l < N_LAYERS; ++l) {
#pragma unroll
            for (int q = 0; q < 4; ++q) {
                const float ct = wc[l * 4 + q], sn = ws[l * 4 + q];
                const int mask = 8 >> q;
#pragma unroll
                for (int idx = 0; idx < 16; ++idx) {
                    if (idx & mask) continue;
                    const int j = idx | mask;
                    float r0 = re[idx], u0 = im[idx], r1 = re[j], u1 = im[j];
                    re[idx] = ct * r0 + sn * u1; im[idx] = ct * u0 - sn * r1;
                    re[j]   = ct * r1 + sn * u0; im[j]   = ct * u1 - sn * r0;
                }
            }
#pragma unroll
            for (int q = 0; q < 4; ++q) {
                const int cm = 8 >> q, tm = 8 >> ((q + 1) & 3);
#pragma unroll
                for (int idx = 0; idx < 16; ++idx) {
                    if ((idx & cm) && !(idx & tm)) {
                        const int j = idx | tm;
                        float t0 = re[idx]; re[idx] = re[j]; re[j] = t0;
                        float t1 = im[idx]; im[idx] = im[j]; im[j] = t1;
                    }
                }
            }
        }
#pragma unroll
        for (int k = 0; k < 16; ++k) { Wr[k][tid] = re[k]; Wi[k][tid] = im[k]; }
    }
    __syncthreads();

    // ---- P2: thread (i,j): S_q[i][j] = sum_k z_q(k) Re(W[k,i] conj(W[k,j]))
    {
        const int i = tid >> 4, j = tid & 15;
        float a0 = 0.f, a1 = 0.f, a2 = 0.f, a3 = 0.f;
#pragma unroll
        for (int k = 0; k < 16; ++k) {
            const float p = Wr[k][i] * Wr[k][j] + Wi[k][i] * Wi[k][j];
            a0 += (k & 8) ? -p : p;
            a1 += (k & 4) ? -p : p;
            a2 += (k & 2) ? -p : p;
            a3 += (k & 1) ? -p : p;
        }
        S4[0][i][j] = a0; S4[1][i][j] = a1; S4[2][i][j] = a2; S4[3][i][j] = a3;
    }
    __syncthreads();

    // ---- P3: C_q[t] = (1/16) sum_i (-1)^popc(i&zm) S_q[i][i^xm]  -> LDS
    if (tid < 81) {
        const int t1 = tid / 27, t2 = (tid / 9) % 3, t3 = (tid / 3) % 3, t4 = tid % 3;
        int zm = 0, xm = 0;
        if (t1 == 1) zm |= 8; else if (t1 == 2) xm |= 8;
        if (t2 == 1) zm |= 4; else if (t2 == 2) xm |= 4;
        if (t3 == 1) zm |= 2; else if (t3 == 2) xm |= 2;
        if (t4 == 1) zm |= 1; else if (t4 == 2) xm |= 1;
        vf4 c;
#pragma unroll
        for (int q = 0; q < 4; ++q) {
            float acc = 0.f;
#pragma unroll
            for (int i = 0; i < 16; ++i) {
                const float v = S4[q][i][i ^ xm];
                acc += (__popc(i & zm) & 1) ? -v : v;
            }
            c[q] = acc * 0.0625f;
        }
        Cs[tid] = c;
    }
    __syncthreads();

    // ---- Phase E: features for both samples (1D arrays + scalars only)
    float u9a[9], w9a[9], u9b[9], w9b[9];
    {
        const float c0 = __cosf(x0.x), s0 = __sinf(x0.x);
        const float c1 = __cosf(x0.y), s1 = __sinf(x0.y);
        const float c2 = __cosf(x0.z), s2 = __sinf(x0.z);
        const float c3 = __cosf(x0.w), s3 = __sinf(x0.w);
        u9a[0] = 1.f; u9a[1] = c1;      u9a[2] = s1;
        u9a[3] = c0;  u9a[4] = c0 * c1; u9a[5] = c0 * s1;
        u9a[6] = s0;  u9a[7] = s0 * c1; u9a[8] = s0 * s1;
        w9a[0] = 1.f; w9a[1] = c3;      w9a[2] = s3;
        w9a[3] = c2;  w9a[4] = c2 * c3; w9a[5] = c2 * s3;
        w9a[6] = s2;  w9a[7] = s2 * c3; w9a[8] = s2 * s3;
    }
    {
        const float c0 = __cosf(x1.x), s0 = __sinf(x1.x);
        const float c1 = __cosf(x1.y), s1 = __sinf(x1.y);
        const float c2 = __cosf(x1.z), s2 = __sinf(x1.z);
        const float c3 = __cosf(x1.w), s3 = __sinf(x1.w);
        u9b[0] = 1.f; u9b[1] = c1;      u9b[2] = s1;
        u9b[3] = c0;  u9b[4] = c0 * c1; u9b[5] = c0 * s1;
        u9b[6] = s0;  u9b[7] = s0 * c1; u9b[8] = s0 * s1;
        w9b[0] = 1.f; w9b[1] = c3;      w9b[2] = s3;
        w9b[3] = c2;  w9b[4] = c2 * c3; w9b[5] = c2 * s3;
        w9b[6] = s2;  w9b[7] = s2 * c3; w9b[8] = s2 * s3;
    }

    float oax = 0.f, oay = 0.f, oaz = 0.f, oaw = 0.f;
    float obx = 0.f, oby = 0.f, obz = 0.f, obw = 0.f;
#pragma unroll
    for (int i = 0; i < 9; ++i) {
        float tax = 0.f, tay = 0.f, taz = 0.f, taw = 0.f;
        float tbx = 0.f, tby = 0.f, tbz = 0.f, tbw = 0.f;
#pragma unroll
        for (int j = 0; j < 9; ++j) {
            const vf4 c = Cs[i * 9 + j];      // ds_read_b128, broadcast
            const float wa = w9a[j], wb = w9b[j];
            tax = fmaf(c[0], wa, tax); tay = fmaf(c[1], wa, tay);
            taz = fmaf(c[2], wa, taz); taw = fmaf(c[3], wa, taw);
            tbx = fmaf(c[0], wb, tbx); tby = fmaf(c[1], wb, tby);
            tbz = fmaf(c[2], wb, tbz); tbw = fmaf(c[3], wb, tbw);
        }
        const float ua = u9a[i], ub = u9b[i];
        oax = fmaf(tax, ua, oax); oay = fmaf(tay, ua, oay);
        oaz = fmaf(taz, ua, oaz); oaw = fmaf(taw, ua, oaw);
        obx = fmaf(tbx, ub, obx); oby = fmaf(tby, ub, oby);
        obz = fmaf(tbz, ub, obz); obw = fmaf(tbw, ub, obw);
    }

    float4* __restrict__ ov4 = reinterpret_cast<float4*>(out);
    ov4[b0] = make_float4(oax, oay, oaz, oaw);
    ov4[b1] = make_float4(obx, oby, obz, obw);
}

extern "C" void kernel_launch(void* const* d_in, const int* in_sizes, int n_in,
                              void* d_out, int out_size, void* d_ws, size_t ws_size,
                              hipStream_t stream) {
    const float* x = (const float*)d_in[0];
    const float* weights = (const float*)d_in[1];
    float* out = (float*)d_out;
    const int B = in_sizes[0] / 4;

    // 2048 blocks x 256 threads x 2 samples = 2^20
    const int grid = (B + 511) / 512;
    qfused_kernel<<<grid, 256, 0, stream>>>(x, weights, out, B);
}